// Round 15
// baseline (271.309 us; speedup 1.0000x reference)
//
#include <hip/hip_runtime.h>
#include <hip/hip_bf16.h>
#include <stdint.h>

#define NN 4096
#define DD 512
#define NCLS 512
#define LMARGIN 0.3f
#define NSLOT 128
#define BK 64
#define NTRI 528                  // 32*33/2 triangular 128x128 tiles
#define NPOST 64                  // k_post blocks (64 rows each)

typedef float f32x4 __attribute__((ext_vector_type(4)));
typedef __bf16 bf16x8 __attribute__((ext_vector_type(8)));
typedef unsigned short us8 __attribute__((ext_vector_type(8)));
typedef unsigned int u32;

__device__ __forceinline__ void gld_lds16(const void* g, void* l) {
    __builtin_amdgcn_global_load_lds((const __attribute__((address_space(1))) unsigned int*)g,
                                     (__attribute__((address_space(3))) unsigned int*)l,
                                     16, 0, 0);
}

__device__ __forceinline__ float waveSum(float v) {
#pragma unroll
    for (int s = 32; s > 0; s >>= 1) v += __shfl_down(v, s, 64);
    return v;
}

// ---------- D1: cast+norms (0..1023) | class sums (1024..1535) | totalSum from x (1536..1537) ----------
__global__ void k_pre(const float* __restrict__ x, const int* __restrict__ tgt,
                      __hip_bfloat16* __restrict__ xb, float* __restrict__ sq,
                      float* __restrict__ classSum, float* __restrict__ classCnt,
                      float* __restrict__ totalSum, u32* __restrict__ cnt) {
    int b = blockIdx.x, tid = threadIdx.x;
    if (b < 1024) {
        int lane = tid & 63, wave = tid >> 6;
        int r = b * 4 + wave;                 // one row per wave
        const f32x4* px = (const f32x4*)(x + (size_t)r * DD) + lane * 2;
        f32x4 v0 = px[0], v1 = px[1];
        float s = v0.x * v0.x + v0.y * v0.y + v0.z * v0.z + v0.w * v0.w +
                  v1.x * v1.x + v1.y * v1.y + v1.z * v1.z + v1.w * v1.w;
        us8 o;
        o[0] = __builtin_bit_cast(unsigned short, __float2bfloat16(v0.x));
        o[1] = __builtin_bit_cast(unsigned short, __float2bfloat16(v0.y));
        o[2] = __builtin_bit_cast(unsigned short, __float2bfloat16(v0.z));
        o[3] = __builtin_bit_cast(unsigned short, __float2bfloat16(v0.w));
        o[4] = __builtin_bit_cast(unsigned short, __float2bfloat16(v1.x));
        o[5] = __builtin_bit_cast(unsigned short, __float2bfloat16(v1.y));
        o[6] = __builtin_bit_cast(unsigned short, __float2bfloat16(v1.z));
        o[7] = __builtin_bit_cast(unsigned short, __float2bfloat16(v1.w));
        *(us8*)((unsigned short*)xb + (size_t)r * DD + lane * 8) = o;
        s = waveSum(s);
        if (lane == 0) sq[r] = s;
    } else if (b < 1536) {
        int c = b - 1024;                     // one class per block
        __shared__ int list[128];
        __shared__ int lcnt;
        if (tid == 0) lcnt = 0;
        __syncthreads();
        for (int i = tid; i < NN; i += 256) {
            if (tgt[i] == c) {
                int p = atomicAdd(&lcnt, 1);  // LDS atomic — cheap
                list[p] = i;
            }
        }
        __syncthreads();
        int n = lcnt;
        float s0 = 0.f, s1 = 0.f;
        for (int p = 0; p < n; ++p) {
            const float* row = x + (size_t)list[p] * DD;
            s0 += row[tid];
            s1 += row[tid + 256];
        }
        classSum[(size_t)c * DD + tid] = s0;
        classSum[(size_t)c * DD + tid + 256] = s1;
        if (tid == 0) classCnt[c] = (float)n;
    } else {
        int q = b - 1536;                     // totalSum: 2 blocks x 256 cols over all rows
        int d = q * 256 + tid;
        float s = 0.f;
#pragma unroll 16
        for (int r = 0; r < NN; ++r) s += x[(size_t)r * DD + d];
        totalSum[d] = s;
        if (b == 1537 && tid == 0) *cnt = 0;  // zero the k_post arrival counter
    }
}

// ---------- D2: triangular Gram (0..527) + centroid rowloss filler (528..1039) ----------
__global__ __launch_bounds__(256) void k_main(const __hip_bfloat16* __restrict__ xb,
                                              const float* __restrict__ sq,
                                              const int* __restrict__ tgt,
                                              const float* __restrict__ x,
                                              const float* __restrict__ classSum,
                                              const float* __restrict__ classCnt,
                                              const float* __restrict__ totalSum,
                                              float* __restrict__ pMax,
                                              float* __restrict__ pMin,
                                              float* __restrict__ ctlArr,
                                              float* __restrict__ dccArr) {
    int b = blockIdx.x;
    const int tid = threadIdx.x;
    const int lane = tid & 63, wave = tid >> 6;
    if (b >= NTRI) {
        // centroid-loss filler: 512 blocks x 8 rows (2 per wave)
        int cb = b - NTRI;
#pragma unroll
        for (int h = 0; h < 2; ++h) {
            int i = cb * 8 + wave * 2 + h;
            int t = tgt[i];
            float cn = classCnt[t];
            float rcp = 1.0f / cn;
            float rcn = 1.0f / ((float)NN - cn);
            const f32x4* px = (const f32x4*)(x + (size_t)i * DD) + lane * 2;
            const f32x4* pc = (const f32x4*)(classSum + (size_t)t * DD) + lane * 2;
            const f32x4* pt = (const f32x4*)(totalSum) + lane * 2;
            float scp = 0.f, scn = 0.f, scc = 0.f;
#pragma unroll
            for (int g = 0; g < 2; ++g) {
                f32x4 xv = px[g], cs = pc[g], ts = pt[g];
#pragma unroll
                for (int e = 0; e < 4; ++e) {
                    float ic = cs[e] * rcp;
                    float oc = (ts[e] - cs[e]) * rcn;
                    float a = ic - xv[e], b2 = oc - xv[e], c2 = ic - oc;
                    scp += a * a;
                    scn += b2 * b2;
                    scc += c2 * c2;
                }
            }
            scp = waveSum(scp);
            scn = waveSum(scn);
            scc = waveSum(scc);
            if (lane == 0) {
                ctlArr[i] = fmaxf(sqrtf(scp) - sqrtf(scn) + LMARGIN, 0.f);
                dccArr[i] = sqrtf(scc);
            }
        }
        return;
    }
    // triangular decode: (by, bx) with by <= bx over 32x32 tiles of 128
    int by = 0, rem = b;
    while (rem >= 32 - by) { rem -= 32 - by; ++by; }
    int bx = by + rem;

    __shared__ __align__(16) __hip_bfloat16 As[128 * BK];   // 16 KB
    __shared__ __align__(16) __hip_bfloat16 Bs[128 * BK];   // 16 KB
    const int wr = wave >> 1, wc = wave & 1;
    const int l15 = lane & 15, quad = lane >> 4;
    const __hip_bfloat16* A0 = xb + (size_t)by * 128 * DD;
    const __hip_bfloat16* B0 = xb + (size_t)bx * 128 * DD;
    const int stRow = tid >> 3;
    const int stCol = ((tid & 7) ^ ((tid >> 3) & 7)) * 8;
    char* AsB = (char*)As;
    char* BsB = (char*)Bs;
    const int ldsOff = wave * 1024;

    f32x4 acc[4][4];
    const f32x4 fz = {0.f, 0.f, 0.f, 0.f};
#pragma unroll
    for (int i = 0; i < 4; ++i)
#pragma unroll
        for (int j = 0; j < 4; ++j) acc[i][j] = fz;

    for (int k0 = 0; k0 < DD; k0 += BK) {
#pragma unroll
        for (int n = 0; n < 4; ++n)
            gld_lds16(A0 + (size_t)(n * 32 + stRow) * DD + k0 + stCol, AsB + n * 4096 + ldsOff);
#pragma unroll
        for (int n = 0; n < 4; ++n)
            gld_lds16(B0 + (size_t)(n * 32 + stRow) * DD + k0 + stCol, BsB + n * 4096 + ldsOff);
        __syncthreads();
#pragma unroll
        for (int kk = 0; kk < 2; ++kk) {
            bf16x8 af[4], bfr[4];
#pragma unroll
            for (int t = 0; t < 4; ++t) {
                int row = wr * 64 + t * 16 + l15;
                af[t] = *(const bf16x8*)(As + row * BK + (((kk * 4 + quad) ^ (l15 & 7)) << 3));
            }
#pragma unroll
            for (int t = 0; t < 4; ++t) {
                int row = wc * 64 + t * 16 + l15;
                bfr[t] = *(const bf16x8*)(Bs + row * BK + (((kk * 4 + quad) ^ (l15 & 7)) << 3));
            }
#pragma unroll
            for (int i = 0; i < 4; ++i)
#pragma unroll
                for (int j = 0; j < 4; ++j)
                    acc[i][j] = __builtin_amdgcn_mfma_f32_16x16x32_bf16(af[i], bfr[j], acc[i][j], 0, 0, 0);
        }
        __syncthreads();
    }

    // epilogue on deferred squared distances (R10 scheme, unchanged)
    const int r0 = by * 128 + wr * 64;
    const int c0 = bx * 128 + wc * 64;
    const int rowSlot = bx * 2 + wc;
    const int colSlot = 64 + by * 2 + wr;
    const float NINF = -__builtin_inff(), PINF = __builtin_inff();
    float sqc[4];
    int tct[4];
#pragma unroll
    for (int j = 0; j < 4; ++j) {
        int c = c0 + j * 16 + l15;
        sqc[j] = sq[c];
        tct[j] = tgt[c];
    }
    float cmax[4], cmin[4];
#pragma unroll
    for (int j = 0; j < 4; ++j) { cmax[j] = NINF; cmin[j] = PINF; }

#pragma unroll
    for (int i = 0; i < 4; ++i) {
#pragma unroll
        for (int rg = 0; rg < 4; ++rg) {
            int r = r0 + i * 16 + quad * 4 + rg;
            float sqr = sq[r];
            int rt = tgt[r];
            float rmax = NINF, rmin = PINF;
#pragma unroll
            for (int j = 0; j < 4; ++j) {
                float t2 = -2.0f * acc[i][j][rg];
                float rv = sqc[j] + t2;
                float cv = sqr + t2;
                if (rt == tct[j]) {
                    rmax = fmaxf(rmax, rv);
                    cmax[j] = fmaxf(cmax[j], cv);
                } else {
                    rmin = fminf(rmin, rv);
                    cmin[j] = fminf(cmin[j], cv);
                }
            }
#pragma unroll
            for (int s = 1; s < 16; s <<= 1) {
                rmax = fmaxf(rmax, __shfl_xor(rmax, s, 64));
                rmin = fminf(rmin, __shfl_xor(rmin, s, 64));
            }
            if (l15 == 0) {
                pMax[(size_t)r * NSLOT + rowSlot] = sqr + rmax;
                pMin[(size_t)r * NSLOT + rowSlot] = sqr + rmin;
            }
        }
    }
#pragma unroll
    for (int j = 0; j < 4; ++j) {
        float vmax = cmax[j], vmin = cmin[j];
        vmax = fmaxf(vmax, __shfl_xor(vmax, 16, 64));
        vmax = fmaxf(vmax, __shfl_xor(vmax, 32, 64));
        vmin = fminf(vmin, __shfl_xor(vmin, 16, 64));
        vmin = fminf(vmin, __shfl_xor(vmin, 32, 64));
        if (quad == 0) {
            int c = c0 + j * 16 + l15;
            pMax[(size_t)c * NSLOT + colSlot] = sqc[j] + vmax;
            pMin[(size_t)c * NSLOT + colSlot] = sqc[j] + vmin;
        }
    }
}

// ---------- D3: triplet slot reduce (64 blocks x 64 rows) + last-arriver final sum ----------
__global__ __launch_bounds__(256) void k_post(const int* __restrict__ tgt,
                                              const float* __restrict__ pMax,
                                              const float* __restrict__ pMin,
                                              const float* __restrict__ ctlArr,
                                              const float* __restrict__ dccArr,
                                              float* __restrict__ partial,
                                              u32* __restrict__ cnt,
                                              float* __restrict__ out) {
    int b = blockIdx.x, tid = threadIdx.x;
    int lane = tid & 63, wave = tid >> 6;
    const float NINF = -__builtin_inff(), PINF = __builtin_inff();
    __shared__ float pr[4][3];
    __shared__ int winner;

    float stl = 0.f, sctl = 0.f, sdcc = 0.f;   // lane-0-valid accumulators
#pragma unroll 1
    for (int k = 0; k < 16; ++k) {
        int i = b * 64 + wave * 16 + k;
        int tile2 = (i >> 7) * 2;
        // row-side slots: lane valid iff lane >= tile2; col-side: 64+lane valid iff lane <= tile2+1
        float a0 = (lane >= tile2) ? pMax[(size_t)i * NSLOT + lane] : NINF;
        float a1 = (lane <= tile2 + 1) ? pMax[(size_t)i * NSLOT + 64 + lane] : NINF;
        float b0 = (lane >= tile2) ? pMin[(size_t)i * NSLOT + lane] : PINF;
        float b1 = (lane <= tile2 + 1) ? pMin[(size_t)i * NSLOT + 64 + lane] : PINF;
        float m2a = fmaxf(a0, a1);
        float m2n = fminf(b0, b1);
#pragma unroll
        for (int s = 1; s < 64; s <<= 1) {
            m2a = fmaxf(m2a, __shfl_xor(m2a, s, 64));
            m2n = fminf(m2n, __shfl_xor(m2n, s, 64));
        }
        if (lane == 0) {
            float ap2 = fmaxf(m2a, 1e-12f);
            float an2 = fmaxf(m2n, 1e-12f);
            stl += fmaxf(sqrtf(ap2) - sqrtf(an2) + LMARGIN, 0.f);
            sctl += ctlArr[i];
            sdcc += dccArr[i];
        }
    }
    if (lane == 0) { pr[wave][0] = stl; pr[wave][1] = sctl; pr[wave][2] = sdcc; }
    __syncthreads();
    if (tid == 0) {
        partial[b * 3 + 0] = pr[0][0] + pr[1][0] + pr[2][0] + pr[3][0];
        partial[b * 3 + 1] = pr[0][1] + pr[1][1] + pr[2][1] + pr[3][1];
        partial[b * 3 + 2] = pr[0][2] + pr[1][2] + pr[2][2] + pr[3][2];
        __threadfence();                       // release partial stores
        u32 old = __hip_atomic_fetch_add(cnt, 1u, __ATOMIC_ACQ_REL, __HIP_MEMORY_SCOPE_AGENT);
        winner = (old == NPOST - 1) ? 1 : 0;
    }
    __syncthreads();
    if (winner) {
        if (tid == 0) __threadfence();          // acquire remote partials
        __syncthreads();
        if (wave == 0) {
            float s0 = 0.f, s1 = 0.f, s2 = 0.f;
            if (lane < NPOST) {
                s0 = partial[lane * 3 + 0];
                s1 = partial[lane * 3 + 1];
                s2 = partial[lane * 3 + 2];
            }
#pragma unroll
            for (int s = 1; s < 64; s <<= 1) {
                s0 += __shfl_xor(s0, s, 64);
                s1 += __shfl_xor(s1, s, 64);
                s2 += __shfl_xor(s2, s, 64);
            }
            if (lane == 0) {
                out[0] = s0 * (1.0f / NN);
                out[1] = s1 * (1.0f / NN);
                out[2] = -s2 * (1.0f / NN);
            }
        }
    }
}

extern "C" void kernel_launch(void* const* d_in, const int* in_sizes, int n_in,
                              void* d_out, int out_size, void* d_ws, size_t ws_size,
                              hipStream_t stream) {
    const float* x = (const float*)d_in[0];
    const int* tgt = (const int*)d_in[1];
    float* out = (float*)d_out;
    char* ws = (char*)d_ws;

    size_t o = 0;
    u32* cnt = (u32*)(ws + o);          o += 256;
    float* totalSum = (float*)(ws + o); o += (size_t)DD * 4;
    __hip_bfloat16* xb = (__hip_bfloat16*)(ws + o); o += (size_t)NN * DD * 2;  // 4 MB
    float* sq = (float*)(ws + o);       o += (size_t)NN * 4;
    float* classSum = (float*)(ws + o); o += (size_t)NCLS * DD * 4;            // 1 MB
    float* classCnt = (float*)(ws + o); o += (size_t)NCLS * 4;
    float* pMax = (float*)(ws + o);     o += (size_t)NN * NSLOT * 4;           // 2 MB
    float* pMin = (float*)(ws + o);     o += (size_t)NN * NSLOT * 4;           // 2 MB
    float* ctlArr = (float*)(ws + o);   o += (size_t)NN * 4;
    float* dccArr = (float*)(ws + o);   o += (size_t)NN * 4;
    float* partial = (float*)(ws + o);  o += (size_t)NPOST * 3 * 4;

    k_pre<<<dim3(1538), dim3(256), 0, stream>>>(x, tgt, xb, sq, classSum, classCnt, totalSum, cnt);
    k_main<<<dim3(NTRI + 512), dim3(256), 0, stream>>>(xb, sq, tgt, x, classSum, classCnt, totalSum,
                                                       pMax, pMin, ctlArr, dccArr);
    k_post<<<dim3(NPOST), dim3(256), 0, stream>>>(tgt, pMax, pMin, ctlArr, dccArr, partial, cnt, out);
}

// Round 16
// 124.844 us; speedup vs baseline: 2.1732x; 2.1732x over previous
//
#include <hip/hip_runtime.h>
#include <hip/hip_bf16.h>
#include <stdint.h>

#define NN 4096
#define DD 512
#define NCLS 512
#define LMARGIN 0.3f
#define NSLOT 128
#define BK 64
#define NTRI 528                  // 32*33/2 triangular 128x128 tiles
#define NPOST 64                  // k_post blocks (64 rows each)
#define NTSB 128                  // totalSum blocks (32 rows each)

typedef float f32x4 __attribute__((ext_vector_type(4)));
typedef __bf16 bf16x8 __attribute__((ext_vector_type(8)));
typedef unsigned short us8 __attribute__((ext_vector_type(8)));
typedef unsigned int u32;

__device__ __forceinline__ void gld_lds16(const void* g, void* l) {
    __builtin_amdgcn_global_load_lds((const __attribute__((address_space(1))) unsigned int*)g,
                                     (__attribute__((address_space(3))) unsigned int*)l,
                                     16, 0, 0);
}

__device__ __forceinline__ float waveSum(float v) {
#pragma unroll
    for (int s = 32; s > 0; s >>= 1) v += __shfl_down(v, s, 64);
    return v;
}

// ---------- D1: cast+norms (0..1023) | class sums (1024..1535) | totalSum atomic (1536..1663) ----------
__global__ void k_pre(const float* __restrict__ x, const int* __restrict__ tgt,
                      __hip_bfloat16* __restrict__ xb, float* __restrict__ sq,
                      float* __restrict__ classSum, float* __restrict__ classCnt,
                      float* __restrict__ totalSum) {
    int b = blockIdx.x, tid = threadIdx.x;
    if (b < 1024) {
        int lane = tid & 63, wave = tid >> 6;
        int r = b * 4 + wave;                 // one row per wave
        const f32x4* px = (const f32x4*)(x + (size_t)r * DD) + lane * 2;
        f32x4 v0 = px[0], v1 = px[1];
        float s = v0.x * v0.x + v0.y * v0.y + v0.z * v0.z + v0.w * v0.w +
                  v1.x * v1.x + v1.y * v1.y + v1.z * v1.z + v1.w * v1.w;
        us8 o;
        o[0] = __builtin_bit_cast(unsigned short, __float2bfloat16(v0.x));
        o[1] = __builtin_bit_cast(unsigned short, __float2bfloat16(v0.y));
        o[2] = __builtin_bit_cast(unsigned short, __float2bfloat16(v0.z));
        o[3] = __builtin_bit_cast(unsigned short, __float2bfloat16(v0.w));
        o[4] = __builtin_bit_cast(unsigned short, __float2bfloat16(v1.x));
        o[5] = __builtin_bit_cast(unsigned short, __float2bfloat16(v1.y));
        o[6] = __builtin_bit_cast(unsigned short, __float2bfloat16(v1.z));
        o[7] = __builtin_bit_cast(unsigned short, __float2bfloat16(v1.w));
        *(us8*)((unsigned short*)xb + (size_t)r * DD + lane * 8) = o;
        s = waveSum(s);
        if (lane == 0) sq[r] = s;
    } else if (b < 1536) {
        int c = b - 1024;                     // one class per block
        __shared__ int list[128];
        __shared__ int lcnt;
        if (tid == 0) lcnt = 0;
        __syncthreads();
        for (int i = tid; i < NN; i += 256) {
            if (tgt[i] == c) {
                int p = atomicAdd(&lcnt, 1);  // LDS atomic — cheap
                list[p] = i;
            }
        }
        __syncthreads();
        int n = lcnt;
        float s0 = 0.f, s1 = 0.f;
        for (int p = 0; p < n; ++p) {
            const float* row = x + (size_t)list[p] * DD;
            s0 += row[tid];
            s1 += row[tid + 256];
        }
        classSum[(size_t)c * DD + tid] = s0;
        classSum[(size_t)c * DD + tid + 256] = s1;
        if (tid == 0) classCnt[c] = (float)n;
    } else {
        int q = b - 1536;                     // totalSum: 128 blocks x 32 rows, atomic merge
        float s0 = 0.f, s1 = 0.f;
#pragma unroll 4
        for (int rr = 0; rr < 32; ++rr) {
            const float* row = x + (size_t)(q * 32 + rr) * DD;
            s0 += row[tid];
            s1 += row[tid + 256];
        }
        atomicAdd(&totalSum[tid], s0);
        atomicAdd(&totalSum[tid + 256], s1);
    }
}

// ---------- D2: triangular Gram (0..527) + centroid rowloss filler (528..1039) ----------
__global__ __launch_bounds__(256) void k_main(const __hip_bfloat16* __restrict__ xb,
                                              const float* __restrict__ sq,
                                              const int* __restrict__ tgt,
                                              const float* __restrict__ x,
                                              const float* __restrict__ classSum,
                                              const float* __restrict__ classCnt,
                                              const float* __restrict__ totalSum,
                                              float* __restrict__ pMax,
                                              float* __restrict__ pMin,
                                              float* __restrict__ ctlArr,
                                              float* __restrict__ dccArr) {
    int b = blockIdx.x;
    const int tid = threadIdx.x;
    const int lane = tid & 63, wave = tid >> 6;
    if (b >= NTRI) {
        // centroid-loss filler: 512 blocks x 8 rows (2 per wave)
        int cb = b - NTRI;
#pragma unroll
        for (int h = 0; h < 2; ++h) {
            int i = cb * 8 + wave * 2 + h;
            int t = tgt[i];
            float cn = classCnt[t];
            float rcp = 1.0f / cn;
            float rcn = 1.0f / ((float)NN - cn);
            const f32x4* px = (const f32x4*)(x + (size_t)i * DD) + lane * 2;
            const f32x4* pc = (const f32x4*)(classSum + (size_t)t * DD) + lane * 2;
            const f32x4* pt = (const f32x4*)(totalSum) + lane * 2;
            float scp = 0.f, scn = 0.f, scc = 0.f;
#pragma unroll
            for (int g = 0; g < 2; ++g) {
                f32x4 xv = px[g], cs = pc[g], ts = pt[g];
#pragma unroll
                for (int e = 0; e < 4; ++e) {
                    float ic = cs[e] * rcp;
                    float oc = (ts[e] - cs[e]) * rcn;
                    float a = ic - xv[e], b2 = oc - xv[e], c2 = ic - oc;
                    scp += a * a;
                    scn += b2 * b2;
                    scc += c2 * c2;
                }
            }
            scp = waveSum(scp);
            scn = waveSum(scn);
            scc = waveSum(scc);
            if (lane == 0) {
                ctlArr[i] = fmaxf(sqrtf(scp) - sqrtf(scn) + LMARGIN, 0.f);
                dccArr[i] = sqrtf(scc);
            }
        }
        return;
    }
    // triangular decode: (by, bx) with by <= bx over 32x32 tiles of 128
    int by = 0, rem = b;
    while (rem >= 32 - by) { rem -= 32 - by; ++by; }
    int bx = by + rem;

    __shared__ __align__(16) __hip_bfloat16 As[128 * BK];   // 16 KB
    __shared__ __align__(16) __hip_bfloat16 Bs[128 * BK];   // 16 KB
    const int wr = wave >> 1, wc = wave & 1;
    const int l15 = lane & 15, quad = lane >> 4;
    const __hip_bfloat16* A0 = xb + (size_t)by * 128 * DD;
    const __hip_bfloat16* B0 = xb + (size_t)bx * 128 * DD;
    const int stRow = tid >> 3;
    const int stCol = ((tid & 7) ^ ((tid >> 3) & 7)) * 8;
    char* AsB = (char*)As;
    char* BsB = (char*)Bs;
    const int ldsOff = wave * 1024;

    f32x4 acc[4][4];
    const f32x4 fz = {0.f, 0.f, 0.f, 0.f};
#pragma unroll
    for (int i = 0; i < 4; ++i)
#pragma unroll
        for (int j = 0; j < 4; ++j) acc[i][j] = fz;

    for (int k0 = 0; k0 < DD; k0 += BK) {
#pragma unroll
        for (int n = 0; n < 4; ++n)
            gld_lds16(A0 + (size_t)(n * 32 + stRow) * DD + k0 + stCol, AsB + n * 4096 + ldsOff);
#pragma unroll
        for (int n = 0; n < 4; ++n)
            gld_lds16(B0 + (size_t)(n * 32 + stRow) * DD + k0 + stCol, BsB + n * 4096 + ldsOff);
        __syncthreads();
#pragma unroll
        for (int kk = 0; kk < 2; ++kk) {
            bf16x8 af[4], bfr[4];
#pragma unroll
            for (int t = 0; t < 4; ++t) {
                int row = wr * 64 + t * 16 + l15;
                af[t] = *(const bf16x8*)(As + row * BK + (((kk * 4 + quad) ^ (l15 & 7)) << 3));
            }
#pragma unroll
            for (int t = 0; t < 4; ++t) {
                int row = wc * 64 + t * 16 + l15;
                bfr[t] = *(const bf16x8*)(Bs + row * BK + (((kk * 4 + quad) ^ (l15 & 7)) << 3));
            }
#pragma unroll
            for (int i = 0; i < 4; ++i)
#pragma unroll
                for (int j = 0; j < 4; ++j)
                    acc[i][j] = __builtin_amdgcn_mfma_f32_16x16x32_bf16(af[i], bfr[j], acc[i][j], 0, 0, 0);
        }
        __syncthreads();
    }

    // epilogue on deferred squared distances (R10 scheme, unchanged)
    const int r0 = by * 128 + wr * 64;
    const int c0 = bx * 128 + wc * 64;
    const int rowSlot = bx * 2 + wc;
    const int colSlot = 64 + by * 2 + wr;
    const float NINF = -__builtin_inff(), PINF = __builtin_inff();
    float sqc[4];
    int tct[4];
#pragma unroll
    for (int j = 0; j < 4; ++j) {
        int c = c0 + j * 16 + l15;
        sqc[j] = sq[c];
        tct[j] = tgt[c];
    }
    float cmax[4], cmin[4];
#pragma unroll
    for (int j = 0; j < 4; ++j) { cmax[j] = NINF; cmin[j] = PINF; }

#pragma unroll
    for (int i = 0; i < 4; ++i) {
#pragma unroll
        for (int rg = 0; rg < 4; ++rg) {
            int r = r0 + i * 16 + quad * 4 + rg;
            float sqr = sq[r];
            int rt = tgt[r];
            float rmax = NINF, rmin = PINF;
#pragma unroll
            for (int j = 0; j < 4; ++j) {
                float t2 = -2.0f * acc[i][j][rg];
                float rv = sqc[j] + t2;
                float cv = sqr + t2;
                if (rt == tct[j]) {
                    rmax = fmaxf(rmax, rv);
                    cmax[j] = fmaxf(cmax[j], cv);
                } else {
                    rmin = fminf(rmin, rv);
                    cmin[j] = fminf(cmin[j], cv);
                }
            }
#pragma unroll
            for (int s = 1; s < 16; s <<= 1) {
                rmax = fmaxf(rmax, __shfl_xor(rmax, s, 64));
                rmin = fminf(rmin, __shfl_xor(rmin, s, 64));
            }
            if (l15 == 0) {
                pMax[(size_t)r * NSLOT + rowSlot] = sqr + rmax;
                pMin[(size_t)r * NSLOT + rowSlot] = sqr + rmin;
            }
        }
    }
#pragma unroll
    for (int j = 0; j < 4; ++j) {
        float vmax = cmax[j], vmin = cmin[j];
        vmax = fmaxf(vmax, __shfl_xor(vmax, 16, 64));
        vmax = fmaxf(vmax, __shfl_xor(vmax, 32, 64));
        vmin = fminf(vmin, __shfl_xor(vmin, 16, 64));
        vmin = fminf(vmin, __shfl_xor(vmin, 32, 64));
        if (quad == 0) {
            int c = c0 + j * 16 + l15;
            pMax[(size_t)c * NSLOT + colSlot] = sqc[j] + vmax;
            pMin[(size_t)c * NSLOT + colSlot] = sqc[j] + vmin;
        }
    }
}

// ---------- D3: triplet slot reduce (64 blocks x 64 rows) + last-arriver final sum ----------
__global__ __launch_bounds__(256) void k_post(const int* __restrict__ tgt,
                                              const float* __restrict__ pMax,
                                              const float* __restrict__ pMin,
                                              const float* __restrict__ ctlArr,
                                              const float* __restrict__ dccArr,
                                              float* __restrict__ partial,
                                              u32* __restrict__ cnt,
                                              float* __restrict__ out) {
    int b = blockIdx.x, tid = threadIdx.x;
    int lane = tid & 63, wave = tid >> 6;
    const float NINF = -__builtin_inff(), PINF = __builtin_inff();
    __shared__ float pr[4][3];
    __shared__ int winner;

    float stl = 0.f, sctl = 0.f, sdcc = 0.f;   // lane-0-valid accumulators
#pragma unroll 1
    for (int k = 0; k < 16; ++k) {
        int i = b * 64 + wave * 16 + k;
        int tile2 = (i >> 7) * 2;
        // row-side slots: lane valid iff lane >= tile2; col-side: 64+lane valid iff lane <= tile2+1
        float a0 = (lane >= tile2) ? pMax[(size_t)i * NSLOT + lane] : NINF;
        float a1 = (lane <= tile2 + 1) ? pMax[(size_t)i * NSLOT + 64 + lane] : NINF;
        float b0 = (lane >= tile2) ? pMin[(size_t)i * NSLOT + lane] : PINF;
        float b1 = (lane <= tile2 + 1) ? pMin[(size_t)i * NSLOT + 64 + lane] : PINF;
        float m2a = fmaxf(a0, a1);
        float m2n = fminf(b0, b1);
#pragma unroll
        for (int s = 1; s < 64; s <<= 1) {
            m2a = fmaxf(m2a, __shfl_xor(m2a, s, 64));
            m2n = fminf(m2n, __shfl_xor(m2n, s, 64));
        }
        if (lane == 0) {
            float ap2 = fmaxf(m2a, 1e-12f);
            float an2 = fmaxf(m2n, 1e-12f);
            stl += fmaxf(sqrtf(ap2) - sqrtf(an2) + LMARGIN, 0.f);
            sctl += ctlArr[i];
            sdcc += dccArr[i];
        }
    }
    if (lane == 0) { pr[wave][0] = stl; pr[wave][1] = sctl; pr[wave][2] = sdcc; }
    __syncthreads();
    if (tid == 0) {
        partial[b * 3 + 0] = pr[0][0] + pr[1][0] + pr[2][0] + pr[3][0];
        partial[b * 3 + 1] = pr[0][1] + pr[1][1] + pr[2][1] + pr[3][1];
        partial[b * 3 + 2] = pr[0][2] + pr[1][2] + pr[2][2] + pr[3][2];
        __threadfence();                       // release partial stores
        u32 old = __hip_atomic_fetch_add(cnt, 1u, __ATOMIC_ACQ_REL, __HIP_MEMORY_SCOPE_AGENT);
        winner = (old == NPOST - 1) ? 1 : 0;
    }
    __syncthreads();
    if (winner) {
        if (tid == 0) __threadfence();          // acquire remote partials
        __syncthreads();
        if (wave == 0) {
            float s0 = 0.f, s1 = 0.f, s2 = 0.f;
            if (lane < NPOST) {
                s0 = partial[lane * 3 + 0];
                s1 = partial[lane * 3 + 1];
                s2 = partial[lane * 3 + 2];
            }
#pragma unroll
            for (int s = 1; s < 64; s <<= 1) {
                s0 += __shfl_xor(s0, s, 64);
                s1 += __shfl_xor(s1, s, 64);
                s2 += __shfl_xor(s2, s, 64);
            }
            if (lane == 0) {
                out[0] = s0 * (1.0f / NN);
                out[1] = s1 * (1.0f / NN);
                out[2] = -s2 * (1.0f / NN);
            }
        }
    }
}

extern "C" void kernel_launch(void* const* d_in, const int* in_sizes, int n_in,
                              void* d_out, int out_size, void* d_ws, size_t ws_size,
                              hipStream_t stream) {
    const float* x = (const float*)d_in[0];
    const int* tgt = (const int*)d_in[1];
    float* out = (float*)d_out;
    char* ws = (char*)d_ws;

    size_t o = 0;
    u32* cnt = (u32*)(ws + o);          o += 256;
    float* totalSum = (float*)(ws + o); o += (size_t)DD * 4;                   // zeroed by memset
    __hip_bfloat16* xb = (__hip_bfloat16*)(ws + o); o += (size_t)NN * DD * 2;  // 4 MB
    float* sq = (float*)(ws + o);       o += (size_t)NN * 4;
    float* classSum = (float*)(ws + o); o += (size_t)NCLS * DD * 4;            // 1 MB
    float* classCnt = (float*)(ws + o); o += (size_t)NCLS * 4;
    float* pMax = (float*)(ws + o);     o += (size_t)NN * NSLOT * 4;           // 2 MB
    float* pMin = (float*)(ws + o);     o += (size_t)NN * NSLOT * 4;           // 2 MB
    float* ctlArr = (float*)(ws + o);   o += (size_t)NN * 4;
    float* dccArr = (float*)(ws + o);   o += (size_t)NN * 4;
    float* partial = (float*)(ws + o);  o += (size_t)NPOST * 3 * 4;

    hipMemsetAsync(ws, 0, 256 + DD * 4, stream);   // zero cnt + totalSum
    k_pre<<<dim3(1536 + NTSB), dim3(256), 0, stream>>>(x, tgt, xb, sq, classSum, classCnt, totalSum);
    k_main<<<dim3(NTRI + 512), dim3(256), 0, stream>>>(xb, sq, tgt, x, classSum, classCnt, totalSum,
                                                       pMax, pMin, ctlArr, dccArr);
    k_post<<<dim3(NPOST), dim3(256), 0, stream>>>(tgt, pMax, pMin, ctlArr, dccArr, partial, cnt, out);
}